// Round 5
// baseline (121.015 us; speedup 1.0000x reference)
//
#include <hip/hip_runtime.h>
#include <hip/hip_bf16.h>

#define IN_DIM 2048
#define OUT_DIM 2048
#define NE 8
#define M_TOT 8192          // B*S = 4*2048
#define RANK_PAD 128        // 8 shared + 64 expert + 24 zero + 32 align pad
#define K_EXT 2176          // IN_DIM + RANK_PAD, divisible by 64
#define NKT 34              // K_EXT / 64

typedef short short8 __attribute__((ext_vector_type(8)));
typedef float floatx4 __attribute__((ext_vector_type(4)));
typedef float floatx16 __attribute__((ext_vector_type(16)));
typedef unsigned short us;

__device__ __forceinline__ us f2bf(float f) {
    __hip_bfloat16 h = __float2bfloat16(f);   // native cast -> v_cvt_pk_bf16_f32 (RNE)
    return *reinterpret_cast<us*>(&h);
}

__device__ __forceinline__ void gld_lds16(const void* g, void* l) {
    __builtin_amdgcn_global_load_lds(
        (const __attribute__((address_space(1))) void*)g,
        (__attribute__((address_space(3))) void*)l, 16, 0, 0);
}

// ---------------------------------------------------------------------------
// 256x256 GEMM, R4 schedule (read-ahead + counted lgkm/vmcnt), R5: MFMA shape
// switched 16x16x32 -> 32x32x16 (m119: 2495 vs 2176 TF ceiling; halves inst
// count). LDS layout/staging/swizzle/sync UNCHANGED from R4:
//   buffer b at b*65536: A.K0 @0, B.K0 @16384, A.K1 @32768, B.K1 @49152
//   (each 16KB = 256 rows x 32 cols bf16; row = 64B = 4 x 16B slots)
//   slot swizzle ps = s ^ ((row>>1)&3), both sides (rule #21).
// 32x32x16 fragments: A-frag(mi,ks): lane reads row=(wm*128+mi*32+(l&31)),
// 16B at slot (ks&1)*2 + (l>>5) of k-half ks>>1. Bank check (per-8-lane
// groups): rows 0..7 at fixed s -> quads {s,4+s,s^1,4+s^1,...} all distinct
// -> conflict-free. C/D: col=l&31, row=(reg&3)+8*(reg>>2)+4*(l>>5) (m74/m101).
// Phases (= R4): p0 MFMA(mq0,kh0) | p1 (mq1,kh0) | p2 (mq1,kh1) | p3 (mq0,kh1)
// with fragment reads one phase ahead, lgkm(4/8), vmcnt(8/8) at p0/p2.
// ---------------------------------------------------------------------------

__device__ __forceinline__ void stage2(const us* src, char* lds) {
    gld_lds16(src, lds);
    gld_lds16(src + 128 * K_EXT, lds + 8192);
}

__device__ __forceinline__ void rd_af(short8 (&d)[4], const char* sm, int kh, int mq,
                                      int ab, int so0, int so1) {
    const char* p = sm + kh * 32768 + ab + mq * 4096;
    d[0] = *(const short8*)(p + so0);
    d[1] = *(const short8*)(p + so1);
    d[2] = *(const short8*)(p + 2048 + so0);
    d[3] = *(const short8*)(p + 2048 + so1);
}

__device__ __forceinline__ void rd_bf(short8 (&d)[4], const char* sm, int kh,
                                      int bb, int so0, int so1) {
    const char* p = sm + kh * 32768 + bb;
    d[0] = *(const short8*)(p + so0);
    d[1] = *(const short8*)(p + so1);
    d[2] = *(const short8*)(p + 2048 + so0);
    d[3] = *(const short8*)(p + 2048 + so1);
}

__device__ __forceinline__ void mfma_oct(floatx16 (&acc)[4][2], const short8 (&af)[4],
                                         const short8 (&bf)[4], int mq) {
#pragma unroll
    for (int ks = 0; ks < 2; ++ks)
#pragma unroll
        for (int ml = 0; ml < 2; ++ml)
#pragma unroll
            for (int nj = 0; nj < 2; ++nj)
                acc[mq * 2 + ml][nj] = __builtin_amdgcn_mfma_f32_32x32x16_bf16(
                    af[ml * 2 + ks], bf[nj * 2 + ks], acc[mq * 2 + ml][nj], 0, 0, 0);
}

template <int SM, int VM0, int VM2, bool RD3>
__device__ __forceinline__ void ktile(
    const us* __restrict__ pA, const us* __restrict__ pB, int k1, int k2,
    const char* smC, const char* smN, char* lwC, char* lwN,
    int ab, int bb, int so0, int so1,
    short8 (&afA)[4], short8 (&afB)[4], short8 (&bfA)[4], short8 (&bfB)[4],
    floatx16 (&acc)[4][2])
{
    // ---------- p0: MFMA(mq0,kh0); read ahead afB=(mq1,kh0) ----------
    rd_af(afB, smC, 0, 1, ab, so0, so1);
    asm volatile("s_waitcnt lgkmcnt(4)" ::: "memory");
    __builtin_amdgcn_sched_barrier(0);
    __builtin_amdgcn_s_setprio(1);
    mfma_oct(acc, afA, bfA, 0);
    __builtin_amdgcn_s_setprio(0);
    if (SM & 1) stage2(pA + k1 + 32, lwN + 32768);
    if (VM0 == 8)      asm volatile("s_waitcnt vmcnt(8)" ::: "memory");
    else if (VM0 == 0) asm volatile("s_waitcnt vmcnt(0)" ::: "memory");
    __builtin_amdgcn_s_barrier();

    // ---------- p1: MFMA(mq1,kh0); read ahead afA=(mq1,kh1), bfB=kh1 ----------
    rd_af(afA, smC, 1, 1, ab, so0, so1);
    rd_bf(bfB, smC, 1, bb, so0, so1);
    asm volatile("s_waitcnt lgkmcnt(8)" ::: "memory");
    __builtin_amdgcn_sched_barrier(0);
    __builtin_amdgcn_s_setprio(1);
    mfma_oct(acc, afB, bfA, 1);
    __builtin_amdgcn_s_setprio(0);
    if (SM & 2) stage2(pB + k2, lwC + 16384);
    __builtin_amdgcn_s_barrier();

    // ---------- p2: MFMA(mq1,kh1); read ahead afB=(mq0,kh1) ----------
    rd_af(afB, smC, 1, 0, ab, so0, so1);
    asm volatile("s_waitcnt lgkmcnt(4)" ::: "memory");
    __builtin_amdgcn_sched_barrier(0);
    __builtin_amdgcn_s_setprio(1);
    mfma_oct(acc, afA, bfB, 1);
    __builtin_amdgcn_s_setprio(0);
    if (SM & 4) stage2(pA + k2, lwC);
    if (VM2 == 8)      asm volatile("s_waitcnt vmcnt(8)" ::: "memory");
    else if (VM2 == 4) asm volatile("s_waitcnt vmcnt(4)" ::: "memory");
    __builtin_amdgcn_s_barrier();

    // ---------- p3: MFMA(mq0,kh1); read ahead next tile (mq0,kh0) + bf kh0 ----------
    if (RD3) {
        rd_af(afA, smN, 0, 0, ab, so0, so1);
        rd_bf(bfA, smN, 0, bb, so0, so1);
        asm volatile("s_waitcnt lgkmcnt(8)" ::: "memory");
    } else {
        asm volatile("s_waitcnt lgkmcnt(0)" ::: "memory");
    }
    __builtin_amdgcn_sched_barrier(0);
    __builtin_amdgcn_s_setprio(1);
    mfma_oct(acc, afB, bfB, 0);
    __builtin_amdgcn_s_setprio(0);
    if (SM & 8) stage2(pB + k2 + 32, lwC + 49152);
    __builtin_amdgcn_s_barrier();
}

__global__ __launch_bounds__(512) void main_gemm8(const us* __restrict__ A,
                                                  const us* __restrict__ B,
                                                  const float* __restrict__ bias,
                                                  float* __restrict__ out) {
    extern __shared__ char smem[];
    int tid = threadIdx.x;
    int lane = tid & 63, w = tid >> 6;
    int wm = w >> 2, wn = w & 3;          // 2M x 4N waves; per-wave C = 128x64
    int rl = lane & 31, hi = lane >> 5;
    int swl = (rl >> 1) & 3;

    // XCD-chunked swizzle: 256 blocks = 8 XCDs x 32
    int b = blockIdx.x;
    int bs = (b & 7) * 32 + (b >> 3);
    int m0 = (bs >> 3) * 256, n0 = (bs & 7) * 256;

    int ab = (wm * 128 + rl) * 64;            // + mi*2048 (pair stride 4096) + kh*32768
    int bb = 16384 + (wn * 64 + rl) * 64;     // + nj*2048 + kh*32768
    int so0 = (hi ^ swl) * 16;
    int so1 = ((2 + hi) ^ swl) * 16;

    // staging source pointers (pre-swizzled global, rule #21)
    int r0 = tid >> 2;
    int ps = tid & 3;
    int ssw = (ps ^ ((r0 >> 1) & 3)) * 8;
    const us* pA = A + (size_t)(m0 + r0) * K_EXT + ssw;
    const us* pB = B + (size_t)(n0 + r0) * K_EXT + ssw;
    char* lw0 = smem + w * 1024;
    char* lw1 = lw0 + 65536;
    const char* sm0 = smem;
    const char* sm1 = smem + 65536;

    floatx16 acc[4][2];
#pragma unroll
    for (int mi = 0; mi < 4; ++mi)
#pragma unroll
        for (int nj = 0; nj < 2; ++nj) acc[mi][nj] = (floatx16)0.f;

    // prologue: 7 halves (tile0 complete; tile1 A.K0,B.K0,B.K1)
    stage2(pA,      lw0);              // A.K0(0)
    stage2(pB,      lw0 + 16384);      // B.K0(0)
    stage2(pA + 32, lw0 + 32768);      // A.K1(0)
    stage2(pB + 32, lw0 + 49152);      // B.K1(0)
    stage2(pA + 64, lw1);              // A.K0(1)
    stage2(pB + 64, lw1 + 16384);      // B.K0(1)
    stage2(pB + 96, lw1 + 49152);      // B.K1(1)
    asm volatile("s_waitcnt vmcnt(10)" ::: "memory");   // tile0 A.K0/B.K0 landed
    __builtin_amdgcn_s_barrier();

    short8 afA[4], afB[4], bfA[4], bfB[4];
    rd_af(afA, sm0, 0, 0, ab, so0, so1);
    rd_bf(bfA, sm0, 0, bb, so0, so1);

    for (int tt = 0; tt < 16; ++tt) {
        int t0 = tt * 2;
        ktile<0xF, 8, 8, true>(pA, pB, (t0 + 1) * 64, (t0 + 2) * 64,
                               sm0, sm1, lw0, lw1, ab, bb, so0, so1,
                               afA, afB, bfA, bfB, acc);
        ktile<0xF, 8, 8, true>(pA, pB, (t0 + 2) * 64, (t0 + 3) * 64,
                               sm1, sm0, lw1, lw0, ab, bb, so0, so1,
                               afA, afB, bfA, bfB, acc);
    }
    ktile<0x1, 8, 4, true>(pA, pB, 33 * 64, 34 * 64,
                           sm0, sm1, lw0, lw1, ab, bb, so0, so1,
                           afA, afB, bfA, bfB, acc);
    ktile<0x0, 0, -1, false>(pA, pB, 0, 0,
                             sm1, sm0, lw1, lw0, ab, bb, so0, so1,
                             afA, afB, bfA, bfB, acc);

    // epilogue: C/D map col=rl, row=(reg&3)+8*(reg>>2)+4*hi
    float bb2[2];
#pragma unroll
    for (int nj = 0; nj < 2; ++nj) bb2[nj] = bias[n0 + wn * 64 + nj * 32 + rl];
#pragma unroll
    for (int mi = 0; mi < 4; ++mi) {
#pragma unroll
        for (int nj = 0; nj < 2; ++nj) {
            int col = n0 + wn * 64 + nj * 32 + rl;
#pragma unroll
            for (int reg = 0; reg < 16; ++reg) {
                int row = m0 + wm * 128 + mi * 32 + (reg & 3) + 8 * (reg >> 2) + 4 * hi;
                out[(size_t)row * OUT_DIM + col] = acc[mi][nj][reg] + bb2[nj];
            }
        }
    }
}

// ---------------------------------------------------------------------------
// prep_wb: blocks 0..2047: W row -> bf16 B_ext row + B_cat cols 2048+.
//          blocks 2048..2143: A_catT row (column k' of [A_s | A_e...]).
// ---------------------------------------------------------------------------
__global__ void prep_wb(const float* __restrict__ W, const float* __restrict__ Bs,
                        const float* __restrict__ Be, const float* __restrict__ As,
                        const float* __restrict__ Ae, us* __restrict__ Bext,
                        us* __restrict__ AcatT) {
    int blk = blockIdx.x;
    int t = threadIdx.x;
    if (blk < OUT_DIM) {
        int n = blk;
        const float4* src = (const float4*)(W + (size_t)n * IN_DIM + t * 8);
        float4 v0 = src[0], v1 = src[1];
        short8 o;
        o[0] = (short)f2bf(v0.x); o[1] = (short)f2bf(v0.y); o[2] = (short)f2bf(v0.z); o[3] = (short)f2bf(v0.w);
        o[4] = (short)f2bf(v1.x); o[5] = (short)f2bf(v1.y); o[6] = (short)f2bf(v1.z); o[7] = (short)f2bf(v1.w);
        *(short8*)(Bext + (size_t)n * K_EXT + t * 8) = o;
        if (t < RANK_PAD) {
            float v = 0.f;
            if (t < 8)       v = Bs[(size_t)t * OUT_DIM + n];
            else if (t < 72) v = Be[(size_t)(t - 8) * OUT_DIM + n];
            Bext[(size_t)n * K_EXT + IN_DIM + t] = f2bf(v);
        }
    } else {
        int kp = blk - OUT_DIM;       // 0..95
        int i0 = t * 8;
        short8 o;
#pragma unroll
        for (int j = 0; j < 8; ++j) {
            int i = i0 + j;
            float v = 0.f;
            if (kp < 8)       v = As[(size_t)i * 8 + kp];
            else if (kp < 72) v = Ae[(size_t)((kp - 8) >> 3) * IN_DIM * 8 + (size_t)i * 8 + ((kp - 8) & 7)];
            o[j] = (short)f2bf(v);
        }
        *(short8*)(AcatT + (size_t)kp * IN_DIM + i0) = o;
    }
}

// ---------------------------------------------------------------------------
// tgemm_fused: reads x (f32), writes bf16 x into A_ext[:,0:2048], computes
// T = x@A_cat (rank 96) K-split across 4 waves + LDS reduce, writes
// routed/scaled T (bf16) into A_ext cols 2048..2143, zeros 2144..2175.
// ---------------------------------------------------------------------------
__global__ __launch_bounds__(256) void tgemm_fused(const float* __restrict__ x,
                                                   us* __restrict__ Aext,
                                                   const us* __restrict__ AcatT,
                                                   const float* __restrict__ routing) {
    __shared__ floatx4 red[4][64][6];
    int tid = threadIdx.x;
    int lane = tid & 63, w = tid >> 6;
    int rlo = lane & 15, kq = lane >> 4;
    int mbase = blockIdx.x * 16;

    floatx4 acc[6];
#pragma unroll
    for (int ni = 0; ni < 6; ++ni) acc[ni] = (floatx4)0.f;

    const float* xrow = x + (size_t)(mbase + rlo) * IN_DIM + w * 512 + kq * 8;
    us* arow = Aext + (size_t)(mbase + rlo) * K_EXT + w * 512 + kq * 8;
    const us* bbase = AcatT + (size_t)rlo * IN_DIM + w * 512 + kq * 8;

#pragma unroll 4
    for (int kt = 0; kt < 16; ++kt) {
        int k0 = kt * 32;
        float4 v0 = *(const float4*)(xrow + k0);
        float4 v1 = *(const float4*)(xrow + k0 + 4);
        short8 a;
        a[0] = (short)f2bf(v0.x); a[1] = (short)f2bf(v0.y); a[2] = (short)f2bf(v0.z); a[3] = (short)f2bf(v0.w);
        a[4] = (short)f2bf(v1.x); a[5] = (short)f2bf(v1.y); a[6] = (short)f2bf(v1.z); a[7] = (short)f2bf(v1.w);
        *(short8*)(arow + k0) = a;
#pragma unroll
        for (int ni = 0; ni < 6; ++ni) {
            short8 bfr = *(const short8*)(bbase + (size_t)(ni * 16) * IN_DIM + k0);
            acc[ni] = __builtin_amdgcn_mfma_f32_16x16x32_bf16(a, bfr, acc[ni], 0, 0, 0);
        }
    }

#pragma unroll
    for (int ni = 0; ni < 6; ++ni) red[w][lane][ni] = acc[ni];
    __syncthreads();
    if (w == 0) {
#pragma unroll
        for (int ni = 0; ni < 6; ++ni) {
            floatx4 s = red[0][lane][ni];
#pragma unroll
            for (int ww = 1; ww < 4; ++ww) s += red[ww][lane][ni];
            int col = ni * 16 + rlo;
#pragma unroll
            for (int r = 0; r < 4; ++r) {
                int row = mbase + kq * 4 + r;
                float fac = (col < 8) ? 1.f
                          : (col < 72 ? routing[(row >> 11) * NE + ((col - 8) >> 3)] : 0.f);
                Aext[(size_t)row * K_EXT + IN_DIM + col] = f2bf(s[r] * fac);
            }
        }
#pragma unroll
        for (int c = 0; c < 2; ++c) {
            int col = 96 + c * 16 + rlo;
#pragma unroll
            for (int r = 0; r < 4; ++r)
                Aext[(size_t)(mbase + kq * 4 + r) * K_EXT + IN_DIM + col] = 0;
        }
    }
}

extern "C" void kernel_launch(void* const* d_in, const int* in_sizes, int n_in,
                              void* d_out, int out_size, void* d_ws, size_t ws_size,
                              hipStream_t stream) {
    const float* x   = (const float*)d_in[0];
    const float* rw  = (const float*)d_in[1];
    const float* W   = (const float*)d_in[2];
    const float* bv  = (const float*)d_in[3];
    const float* As  = (const float*)d_in[4];
    const float* Bs  = (const float*)d_in[5];
    const float* Ae  = (const float*)d_in[6];
    const float* Be  = (const float*)d_in[7];
    float* out = (float*)d_out;

    size_t offA = 0;
    size_t offB = offA + (size_t)M_TOT * K_EXT * sizeof(us);
    size_t offC = offB + (size_t)OUT_DIM * K_EXT * sizeof(us);
    size_t need = offC + (size_t)96 * IN_DIM * sizeof(us);
    if (ws_size < need) return;

    us* Aext  = (us*)((char*)d_ws + offA);
    us* Bext  = (us*)((char*)d_ws + offB);
    us* AcatT = (us*)((char*)d_ws + offC);

    hipFuncSetAttribute((const void*)main_gemm8,
                        hipFuncAttributeMaxDynamicSharedMemorySize, 131072);

    prep_wb<<<OUT_DIM + 96, 256, 0, stream>>>(W, Bs, Be, As, Ae, Bext, AcatT);
    tgemm_fused<<<M_TOT / 16, 256, 0, stream>>>(x, Aext, AcatT, rw);
    main_gemm8<<<256, 512, 131072, stream>>>(Aext, Bext, bv, out);
}

// Round 6
// 114.569 us; speedup vs baseline: 1.0563x; 1.0563x over previous
//
#include <hip/hip_runtime.h>
#include <hip/hip_bf16.h>

#define IN_DIM 2048
#define OUT_DIM 2048
#define NE 8
#define M_TOT 8192          // B*S = 4*2048
#define RANK_PAD 128        // 8 shared + 64 expert + 24 zero + 32 align pad
#define K_EXT 2176          // IN_DIM + RANK_PAD, divisible by 64
#define NKT 34              // K_EXT / 64

typedef short short8 __attribute__((ext_vector_type(8)));
typedef float floatx4 __attribute__((ext_vector_type(4)));
typedef unsigned short us;

__device__ __forceinline__ us f2bf(float f) {
    __hip_bfloat16 h = __float2bfloat16(f);   // native RNE cast
    return *reinterpret_cast<us*>(&h);
}

__device__ __forceinline__ void gld_lds16(const void* g, void* l) {
    __builtin_amdgcn_global_load_lds(
        (const __attribute__((address_space(1))) void*)g,
        (__attribute__((address_space(3))) void*)l, 16, 0, 0);
}

// ---------------------------------------------------------------------------
// 256x256 8-phase GEMM with READ-AHEAD register pipelining — EXACT R4 kernel
// (16x16x32 MFMA; R5's 32x32x16 experiment re-introduced a +4cyc/ds_read bank
// conflict (6.68M) and regressed 68.5->75.4us; reverted).
// LDS buffer b at b*65536: A.K0 @0, B.K0 @16384, A.K1 @32768, B.K1 @49152.
// Swizzle (both sides, rule #21): slot ps = s ^ ((row>>1)&3).
// Phases p0..p3 with fragment reads one phase ahead, lgkm(4/8) counted waits,
// vmcnt(8) at p0/p2; stage order A.K1(t+1) | B.K0(t+2) | A.K0(t+2) | B.K1(t+2).
// ---------------------------------------------------------------------------

__device__ __forceinline__ void stage2(const us* src, char* lds) {
    gld_lds16(src, lds);
    gld_lds16(src + 128 * K_EXT, lds + 8192);
}

__device__ __forceinline__ void mfma_quad(floatx4 (&acc)[8][4], const short8 (&af)[4],
                                          const short8 (&bf)[4], int mq) {
#pragma unroll
    for (int i = 0; i < 4; ++i)
#pragma unroll
        for (int ni = 0; ni < 4; ++ni)
            acc[mq * 4 + i][ni] =
                __builtin_amdgcn_mfma_f32_16x16x32_bf16(af[i], bf[ni], acc[mq * 4 + i][ni], 0, 0, 0);
}

template <int SM, int VM0, int VM2, bool RD3>
__device__ __forceinline__ void ktile(
    const us* __restrict__ pA, const us* __restrict__ pB, int k1, int k2,
    const char* smC, const char* smN, char* lwC, char* lwN,
    int ab, int bb,
    short8 (&afA)[4], short8 (&afB)[4], short8 (&bfA)[4], short8 (&bfB)[4],
    floatx4 (&acc)[8][4])
{
    // ---------- p0 ----------
#pragma unroll
    for (int i = 0; i < 4; ++i) afB[i] = *(const short8*)(smC + ab + (4 + i) * 1024);
    asm volatile("s_waitcnt lgkmcnt(4)" ::: "memory");
    __builtin_amdgcn_sched_barrier(0);
    __builtin_amdgcn_s_setprio(1);
    mfma_quad(acc, afA, bfA, 0);
    __builtin_amdgcn_s_setprio(0);
    if (SM & 1) stage2(pA + k1 + 32, lwN + 32768);
    if (VM0 == 8)      asm volatile("s_waitcnt vmcnt(8)" ::: "memory");
    else if (VM0 == 0) asm volatile("s_waitcnt vmcnt(0)" ::: "memory");
    __builtin_amdgcn_s_barrier();

    // ---------- p1 ----------
#pragma unroll
    for (int i = 0; i < 4; ++i) afA[i] = *(const short8*)(smC + 32768 + ab + (4 + i) * 1024);
#pragma unroll
    for (int i = 0; i < 4; ++i) bfB[i] = *(const short8*)(smC + 32768 + bb + i * 1024);
    asm volatile("s_waitcnt lgkmcnt(8)" ::: "memory");
    __builtin_amdgcn_sched_barrier(0);
    __builtin_amdgcn_s_setprio(1);
    mfma_quad(acc, afB, bfA, 1);
    __builtin_amdgcn_s_setprio(0);
    if (SM & 2) stage2(pB + k2, lwC + 16384);
    __builtin_amdgcn_s_barrier();

    // ---------- p2 ----------
#pragma unroll
    for (int i = 0; i < 4; ++i) afB[i] = *(const short8*)(smC + 32768 + ab + i * 1024);
    asm volatile("s_waitcnt lgkmcnt(4)" ::: "memory");
    __builtin_amdgcn_sched_barrier(0);
    __builtin_amdgcn_s_setprio(1);
    mfma_quad(acc, afA, bfB, 1);
    __builtin_amdgcn_s_setprio(0);
    if (SM & 4) stage2(pA + k2, lwC);
    if (VM2 == 8)      asm volatile("s_waitcnt vmcnt(8)" ::: "memory");
    else if (VM2 == 4) asm volatile("s_waitcnt vmcnt(4)" ::: "memory");
    __builtin_amdgcn_s_barrier();

    // ---------- p3 ----------
    if (RD3) {
#pragma unroll
        for (int i = 0; i < 4; ++i) afA[i] = *(const short8*)(smN + ab + i * 1024);
#pragma unroll
        for (int i = 0; i < 4; ++i) bfA[i] = *(const short8*)(smN + bb + i * 1024);
        asm volatile("s_waitcnt lgkmcnt(8)" ::: "memory");
    } else {
        asm volatile("s_waitcnt lgkmcnt(0)" ::: "memory");
    }
    __builtin_amdgcn_sched_barrier(0);
    __builtin_amdgcn_s_setprio(1);
    mfma_quad(acc, afB, bfB, 0);
    __builtin_amdgcn_s_setprio(0);
    if (SM & 8) stage2(pB + k2 + 32, lwC + 49152);
    __builtin_amdgcn_s_barrier();
}

__global__ __launch_bounds__(512) void main_gemm8(const us* __restrict__ A,
                                                  const us* __restrict__ B,
                                                  const float* __restrict__ bias,
                                                  float* __restrict__ out) {
    extern __shared__ char smem[];
    int tid = threadIdx.x;
    int lane = tid & 63, w = tid >> 6;
    int wm = w >> 2, wn = w & 3;          // 2M x 4N waves; per-wave C = 128x64
    int rlo = lane & 15, kq = lane >> 4;

    // XCD-chunked swizzle: 256 blocks = 8 XCDs x 32
    int b = blockIdx.x;
    int bs = (b & 7) * 32 + (b >> 3);
    int m0 = (bs >> 3) * 256, n0 = (bs & 7) * 256;

    int swz = (kq ^ ((rlo >> 1) & 3)) * 16;
    int ab = (wm * 128 + rlo) * 64 + swz;            // + mi*1024 + kh*32768
    int bb = 16384 + (wn * 64 + rlo) * 64 + swz;     // + ni*1024 + kh*32768

    // staging source pointers (pre-swizzled global, rule #21)
    int r0 = tid >> 2;
    int ps = tid & 3;
    int ssw = (ps ^ ((r0 >> 1) & 3)) * 8;
    const us* pA = A + (size_t)(m0 + r0) * K_EXT + ssw;
    const us* pB = B + (size_t)(n0 + r0) * K_EXT + ssw;
    char* lw0 = smem + w * 1024;
    char* lw1 = lw0 + 65536;
    const char* sm0 = smem;
    const char* sm1 = smem + 65536;

    floatx4 acc[8][4];
#pragma unroll
    for (int mi = 0; mi < 8; ++mi)
#pragma unroll
        for (int ni = 0; ni < 4; ++ni) acc[mi][ni] = (floatx4)0.f;

    // prologue: 7 halves (tile0 complete; tile1 A.K0,B.K0,B.K1)
    stage2(pA,      lw0);              // A.K0(0)
    stage2(pB,      lw0 + 16384);      // B.K0(0)
    stage2(pA + 32, lw0 + 32768);      // A.K1(0)
    stage2(pB + 32, lw0 + 49152);      // B.K1(0)
    stage2(pA + 64, lw1);              // A.K0(1)
    stage2(pB + 64, lw1 + 16384);      // B.K0(1)
    stage2(pB + 96, lw1 + 49152);      // B.K1(1)
    asm volatile("s_waitcnt vmcnt(10)" ::: "memory");   // tile0 A.K0/B.K0 landed
    __builtin_amdgcn_s_barrier();

    short8 afA[4], afB[4], bfA[4], bfB[4];
#pragma unroll
    for (int i = 0; i < 4; ++i) afA[i] = *(const short8*)(sm0 + ab + i * 1024);
#pragma unroll
    for (int i = 0; i < 4; ++i) bfA[i] = *(const short8*)(sm0 + bb + i * 1024);

    for (int tt = 0; tt < 16; ++tt) {
        int t0 = tt * 2;
        ktile<0xF, 8, 8, true>(pA, pB, (t0 + 1) * 64, (t0 + 2) * 64,
                               sm0, sm1, lw0, lw1, ab, bb, afA, afB, bfA, bfB, acc);
        ktile<0xF, 8, 8, true>(pA, pB, (t0 + 2) * 64, (t0 + 3) * 64,
                               sm1, sm0, lw1, lw0, ab, bb, afA, afB, bfA, bfB, acc);
    }
    ktile<0x1, 8, 4, true>(pA, pB, 33 * 64, 34 * 64,
                           sm0, sm1, lw0, lw1, ab, bb, afA, afB, bfA, bfB, acc);
    ktile<0x0, 0, -1, false>(pA, pB, 0, 0,
                             sm1, sm0, lw1, lw0, ab, bb, afA, afB, bfA, bfB, acc);

    // epilogue: C/D map col=rlo, row=kq*4+reg
    float bbias[4];
#pragma unroll
    for (int ni = 0; ni < 4; ++ni) bbias[ni] = bias[n0 + wn * 64 + ni * 16 + rlo];
#pragma unroll
    for (int mi = 0; mi < 8; ++mi) {
        int row = m0 + wm * 128 + mi * 16 + kq * 4;
#pragma unroll
        for (int ni = 0; ni < 4; ++ni) {
            int col = n0 + wn * 64 + ni * 16 + rlo;
#pragma unroll
            for (int r = 0; r < 4; ++r)
                out[(size_t)(row + r) * OUT_DIM + col] = acc[mi][ni][r] + bbias[ni];
        }
    }
}

// ---------------------------------------------------------------------------
// prep_wb: blocks 0..2047: W row -> bf16 B_ext row + B_cat cols 2048+.
//          blocks 2048..2143: A_catT row (column k' of [A_s | A_e...]).
// ---------------------------------------------------------------------------
__global__ void prep_wb(const float* __restrict__ W, const float* __restrict__ Bs,
                        const float* __restrict__ Be, const float* __restrict__ As,
                        const float* __restrict__ Ae, us* __restrict__ Bext,
                        us* __restrict__ AcatT) {
    int blk = blockIdx.x;
    int t = threadIdx.x;
    if (blk < OUT_DIM) {
        int n = blk;
        const float4* src = (const float4*)(W + (size_t)n * IN_DIM + t * 8);
        float4 v0 = src[0], v1 = src[1];
        short8 o;
        o[0] = (short)f2bf(v0.x); o[1] = (short)f2bf(v0.y); o[2] = (short)f2bf(v0.z); o[3] = (short)f2bf(v0.w);
        o[4] = (short)f2bf(v1.x); o[5] = (short)f2bf(v1.y); o[6] = (short)f2bf(v1.z); o[7] = (short)f2bf(v1.w);
        *(short8*)(Bext + (size_t)n * K_EXT + t * 8) = o;
        if (t < RANK_PAD) {
            float v = 0.f;
            if (t < 8)       v = Bs[(size_t)t * OUT_DIM + n];
            else if (t < 72) v = Be[(size_t)(t - 8) * OUT_DIM + n];
            Bext[(size_t)n * K_EXT + IN_DIM + t] = f2bf(v);
        }
    } else {
        int kp = blk - OUT_DIM;       // 0..95
        int i0 = t * 8;
        short8 o;
#pragma unroll
        for (int j = 0; j < 8; ++j) {
            int i = i0 + j;
            float v = 0.f;
            if (kp < 8)       v = As[(size_t)i * 8 + kp];
            else if (kp < 72) v = Ae[(size_t)((kp - 8) >> 3) * IN_DIM * 8 + (size_t)i * 8 + ((kp - 8) & 7)];
            o[j] = (short)f2bf(v);
        }
        *(short8*)(AcatT + (size_t)kp * IN_DIM + i0) = o;
    }
}

// ---------------------------------------------------------------------------
// tgemm_fused (R6): 512 threads, K split 8 ways (256 k per wave) for 2x TLP
// (16 waves/CU) to hide the L2-latency-bound AcatT fragment loads.
// Reads x (f32), writes bf16 x into A_ext[:,0:2048], computes T = x@A_cat
// (rank 96), LDS-reduces over 8 waves, writes routed/scaled T (bf16) into
// A_ext cols 2048..2143, zeros 2144..2175.
// ---------------------------------------------------------------------------
__global__ __launch_bounds__(512) void tgemm_fused(const float* __restrict__ x,
                                                   us* __restrict__ Aext,
                                                   const us* __restrict__ AcatT,
                                                   const float* __restrict__ routing) {
    __shared__ floatx4 red[8][64][6];
    int tid = threadIdx.x;
    int lane = tid & 63, w = tid >> 6;     // wave w owns K range [w*256, w*256+256)
    int rlo = lane & 15, kq = lane >> 4;
    int mbase = blockIdx.x * 16;

    floatx4 acc[6];
#pragma unroll
    for (int ni = 0; ni < 6; ++ni) acc[ni] = (floatx4)0.f;

    const float* xrow = x + (size_t)(mbase + rlo) * IN_DIM + w * 256 + kq * 8;
    us* arow = Aext + (size_t)(mbase + rlo) * K_EXT + w * 256 + kq * 8;
    const us* bbase = AcatT + (size_t)rlo * IN_DIM + w * 256 + kq * 8;

#pragma unroll
    for (int kt = 0; kt < 8; ++kt) {
        int k0 = kt * 32;
        float4 v0 = *(const float4*)(xrow + k0);
        float4 v1 = *(const float4*)(xrow + k0 + 4);
        short8 a;
        a[0] = (short)f2bf(v0.x); a[1] = (short)f2bf(v0.y); a[2] = (short)f2bf(v0.z); a[3] = (short)f2bf(v0.w);
        a[4] = (short)f2bf(v1.x); a[5] = (short)f2bf(v1.y); a[6] = (short)f2bf(v1.z); a[7] = (short)f2bf(v1.w);
        *(short8*)(arow + k0) = a;
#pragma unroll
        for (int ni = 0; ni < 6; ++ni) {
            short8 bfr = *(const short8*)(bbase + (size_t)(ni * 16) * IN_DIM + k0);
            acc[ni] = __builtin_amdgcn_mfma_f32_16x16x32_bf16(a, bfr, acc[ni], 0, 0, 0);
        }
    }

#pragma unroll
    for (int ni = 0; ni < 6; ++ni) red[w][lane][ni] = acc[ni];
    __syncthreads();
    if (w == 0) {
#pragma unroll
        for (int ni = 0; ni < 6; ++ni) {
            floatx4 s = red[0][lane][ni];
#pragma unroll
            for (int ww = 1; ww < 8; ++ww) s += red[ww][lane][ni];
            int col = ni * 16 + rlo;
#pragma unroll
            for (int r = 0; r < 4; ++r) {
                int row = mbase + kq * 4 + r;
                float fac = (col < 8) ? 1.f
                          : (col < 72 ? routing[(row >> 11) * NE + ((col - 8) >> 3)] : 0.f);
                Aext[(size_t)row * K_EXT + IN_DIM + col] = f2bf(s[r] * fac);
            }
        }
#pragma unroll
        for (int c = 0; c < 2; ++c) {
            int col = 96 + c * 16 + rlo;
#pragma unroll
            for (int r = 0; r < 4; ++r)
                Aext[(size_t)(mbase + kq * 4 + r) * K_EXT + IN_DIM + col] = 0;
        }
    }
}

extern "C" void kernel_launch(void* const* d_in, const int* in_sizes, int n_in,
                              void* d_out, int out_size, void* d_ws, size_t ws_size,
                              hipStream_t stream) {
    const float* x   = (const float*)d_in[0];
    const float* rw  = (const float*)d_in[1];
    const float* W   = (const float*)d_in[2];
    const float* bv  = (const float*)d_in[3];
    const float* As  = (const float*)d_in[4];
    const float* Bs  = (const float*)d_in[5];
    const float* Ae  = (const float*)d_in[6];
    const float* Be  = (const float*)d_in[7];
    float* out = (float*)d_out;

    size_t offA = 0;
    size_t offB = offA + (size_t)M_TOT * K_EXT * sizeof(us);
    size_t offC = offB + (size_t)OUT_DIM * K_EXT * sizeof(us);
    size_t need = offC + (size_t)96 * IN_DIM * sizeof(us);
    if (ws_size < need) return;

    us* Aext  = (us*)((char*)d_ws + offA);
    us* Bext  = (us*)((char*)d_ws + offB);
    us* AcatT = (us*)((char*)d_ws + offC);

    hipFuncSetAttribute((const void*)main_gemm8,
                        hipFuncAttributeMaxDynamicSharedMemorySize, 131072);

    prep_wb<<<OUT_DIM + 96, 256, 0, stream>>>(W, Bs, Be, As, Ae, Bext, AcatT);
    tgemm_fused<<<M_TOT / 16, 512, 0, stream>>>(x, Aext, AcatT, rw);
    main_gemm8<<<256, 512, 131072, stream>>>(Aext, Bext, bv, out);
}